// Round 8
// baseline (23349.072 us; speedup 1.0000x reference)
//
#include <hip/hip_runtime.h>
#include <cstddef>

#define NBATCH 64
#define NT     512
#define NH     512

typedef float f32x4 __attribute__((ext_vector_type(4)));

// ---------------------------------------------------------------------------
// Projection GEMM: P[m][n] = sum_k A[m][k]*W[n][k] + b1[n] + b2[n]
// (Unchanged — correctness-proven; rec dominates runtime.)
// ---------------------------------------------------------------------------
template<int K>
__global__ __launch_bounds__(256)
void proj_kernel(const float* __restrict__ A, const float* __restrict__ W,
                 const float* __restrict__ b1, const float* __restrict__ b2,
                 float* __restrict__ P)
{
    __shared__ float a_sh[32 * 132];
    __shared__ float b_sh[32 * 132];

    const int t    = threadIdx.x;
    const int bm   = blockIdx.x & 255;
    const int bn   = blockIdx.x >> 8;
    const int row0 = bm * 128;
    const int col0 = bn * 128;

    const int rm = t & 15;
    const int cn = t >> 4;
    const int sr = t >> 3;
    const int kq = t & 7;

    float acc[8][8];
#pragma unroll
    for (int i = 0; i < 8; ++i)
#pragma unroll
        for (int j = 0; j < 8; ++j) acc[i][j] = 0.f;

    for (int k0 = 0; k0 < K; k0 += 32) {
        __syncthreads();
#pragma unroll
        for (int u = 0; u < 4; ++u) {
            const int r = sr + 32 * u;
            const float4 av = *reinterpret_cast<const float4*>(&A[(size_t)(row0 + r) * K + k0 + kq * 4]);
            const float4 wv = *reinterpret_cast<const float4*>(&W[(size_t)(col0 + r) * K + k0 + kq * 4]);
            a_sh[(kq*4+0)*132 + r] = av.x;  a_sh[(kq*4+1)*132 + r] = av.y;
            a_sh[(kq*4+2)*132 + r] = av.z;  a_sh[(kq*4+3)*132 + r] = av.w;
            b_sh[(kq*4+0)*132 + r] = wv.x;  b_sh[(kq*4+1)*132 + r] = wv.y;
            b_sh[(kq*4+2)*132 + r] = wv.z;  b_sh[(kq*4+3)*132 + r] = wv.w;
        }
        __syncthreads();
#pragma unroll 4
        for (int k = 0; k < 32; ++k) {
            const float4 a0 = *reinterpret_cast<const float4*>(&a_sh[k*132 + rm*4]);
            const float4 a1 = *reinterpret_cast<const float4*>(&a_sh[k*132 + 64 + rm*4]);
            const float4 w0 = *reinterpret_cast<const float4*>(&b_sh[k*132 + cn*4]);
            const float4 w1 = *reinterpret_cast<const float4*>(&b_sh[k*132 + 64 + cn*4]);
            const float ar[8] = {a0.x,a0.y,a0.z,a0.w,a1.x,a1.y,a1.z,a1.w};
            const float br[8] = {w0.x,w0.y,w0.z,w0.w,w1.x,w1.y,w1.z,w1.w};
#pragma unroll
            for (int i = 0; i < 8; ++i)
#pragma unroll
                for (int j = 0; j < 8; ++j)
                    acc[i][j] = fmaf(ar[i], br[j], acc[i][j]);
        }
    }

    float bs[8];
#pragma unroll
    for (int j = 0; j < 8; ++j) {
        const int n = col0 + ((j < 4) ? (cn*4 + j) : (64 + cn*4 + j - 4));
        bs[j] = b1[n] + b2[n];
    }
#pragma unroll
    for (int i = 0; i < 8; ++i) {
        const int m = row0 + ((i < 4) ? (rm*4 + i) : (64 + rm*4 + i - 4));
        float4 v0, v1;
        v0.x = acc[i][0]+bs[0]; v0.y = acc[i][1]+bs[1]; v0.z = acc[i][2]+bs[2]; v0.w = acc[i][3]+bs[3];
        v1.x = acc[i][4]+bs[4]; v1.y = acc[i][5]+bs[5]; v1.z = acc[i][6]+bs[6]; v1.w = acc[i][7]+bs[7];
        *reinterpret_cast<float4*>(&P[(size_t)m * NH + col0 + cn*4])      = v0;
        *reinterpret_cast<float4*>(&P[(size_t)m * NH + col0 + 64 + cn*4]) = v1;
    }
}

// DPP row_shr accumulate (HW-verified rounds 3/7): after shr1+shr2+shr4,
// lanes with (lane&7)==7 hold their 8-group sum.
template<int CTRL>
__device__ __forceinline__ float dpp_shr_add(float x) {
    const int y = __builtin_amdgcn_update_dpp(0, __float_as_int(x), CTRL, 0xF, 0xF, true);
    return x + __int_as_float(y);
}
__device__ __forceinline__ float group8_sum(float x) {
    x = dpp_shr_add<0x111>(x);
    x = dpp_shr_add<0x112>(x);
    x = dpp_shr_add<0x114>(x);
    return x;
}

__device__ __forceinline__ float fast_tanh(float x) {
    x = fminf(15.f, fmaxf(-15.f, x));
    const float e = __expf(2.f * x);
    return (e - 1.f) / (e + 1.f);
}

// W fragment as NAMED ext_vector SSA values (rounds 3/7 post-mortem: C-array
// W was never SROA-promoted -> lived in scratch -> ~20us/step of stack
// reloads at VGPR_Count=88. ext_vectors are first-class SSA, never allocas;
// a global load can't be rematerialized, so they stay in VGPRs or spill
// VISIBLY. Guide rule #20.)
#define DECL_W(i) \
    const f32x4 wa##i = *reinterpret_cast<const f32x4*>(&r0[(i)*4]); \
    const f32x4 wb##i = *reinterpret_cast<const f32x4*>(&r1[(i)*4]);

#define FMA_CHUNK(i) { \
    const f32x4 hv = *reinterpret_cast<const f32x4*>(&hbase[(i)*4]); \
    acc0 = fmaf(wa##i.x, hv.x, acc0); \
    acc0 = fmaf(wa##i.y, hv.y, acc0); \
    acc0 = fmaf(wa##i.z, hv.z, acc0); \
    acc0 = fmaf(wa##i.w, hv.w, acc0); \
    acc1 = fmaf(wb##i.x, hv.x, acc1); \
    acc1 = fmaf(wb##i.y, hv.y, acc1); \
    acc1 = fmaf(wb##i.z, hv.z, acc1); \
    acc1 = fmaf(wb##i.w, hv.w, acc1); }

// ---------------------------------------------------------------------------
// Recurrence: h_t = tanh(P[t] + W_hh @ h_{t-1}), 4 blocks/batch (row quarters),
// 256 blocks x 512 threads = 1 block/CU co-residency (launch_bounds(512,2):
// 8 waves = 2/EU, VGPR budget 256).
// Thread (g=t>>3, sub=t&7) holds rows {q*128+g, q*128+64+g}, cols [sub*64,+64)
// as 32 named f32x4 = 128 VGPRs. Exchange protocol unchanged from round 7
// (passed twice, absmax 0.0): relaxed agent-scope xbuf stores, barrier-drained,
// t0 release flag, distributed acquire spins, double-buffered by parity.
// ---------------------------------------------------------------------------
__global__ __launch_bounds__(512, 2)
void rec_kernel(const float* __restrict__ P,
                const float* __restrict__ Whh,
                float* __restrict__ HS,      // hs_all=1: [B*T][H]; else h_last [B][H]
                float* __restrict__ xbuf,    // [B][4][2][128]
                int*   __restrict__ flags,   // [B][4], pre-zeroed
                int hs_all)
{
    const int t  = threadIdx.x;
    const int bi = blockIdx.x;
    // bid = quad*64 + batch -> bid%8 == batch%8: all 4 quads of a batch on one
    // XCD (assuming %8 round-robin dispatch; wrong mapping only costs perf).
    const int q = bi >> 6;          // quad 0..3
    const int b = bi & 63;          // batch element

    const int sub = t & 7;          // k-chunk (64 floats of h)
    const int g   = t >> 3;         // 0..63

    const float* r0 = &Whh[(size_t)(q*128 +      g) * NH + sub*64];
    const float* r1 = &Whh[(size_t)(q*128 + 64 + g) * NH + sub*64];
    DECL_W(0)  DECL_W(1)  DECL_W(2)  DECL_W(3)
    DECL_W(4)  DECL_W(5)  DECL_W(6)  DECL_W(7)
    DECL_W(8)  DECL_W(9)  DECL_W(10) DECL_W(11)
    DECL_W(12) DECL_W(13) DECL_W(14) DECL_W(15)

    // h double-buffered in LDS; chunk c at base c*68 floats (byte 272*c -> 16B
    // aligned, 8 distinct bank-quads for the 8 sub values): conflict-free b128.
    __shared__ float h_sh[2][8 * 68];
    for (int i = t; i < 2*8*68; i += 512) reinterpret_cast<float*>(h_sh)[i] = 0.f;

    const bool wrt = (sub == 7);               // writer lane of each 8-group
    const int  jg0 = q*128 + g;
    const int  jg1 = q*128 + 64 + g;

    const size_t prow = (size_t)b * NT;
    float p_next0 = 0.f, p_next1 = 0.f;
    if (wrt) {
        p_next0 = P[(prow + 0) * NH + jg0];
        p_next1 = P[(prow + 0) * NH + jg1];
    }

    int*   myflag  = &flags[b*4 + q];
    float* bufbase = &xbuf[((size_t)b*4 + q) * 256];

    // Gather assignment: threads 0..383 in 3 groups of 128 (wave-uniform peer).
    const int pidx = t >> 7;
    const int e    = t & 127;
    const int qp   = pidx + (pidx >= q ? 1 : 0);
    int*   peerflag = &flags[b*4 + qp];
    const float* peerbuf = &xbuf[((size_t)b*4 + qp) * 256];

    __syncthreads();

    for (int step = 0; step < NT; ++step) {
        const int par = step & 1;
        const float p_cur0 = p_next0, p_cur1 = p_next1;
        if (wrt && step + 1 < NT) {
            p_next0 = P[(prow + step + 1) * NH + jg0];
            p_next1 = P[(prow + step + 1) * NH + jg1];
        }

        // Partial dots: register W (named SSA f32x4) x LDS-broadcast h chunk.
        float acc0 = 0.f, acc1 = 0.f;
        const float* hbase = &h_sh[par][sub * 68];
        FMA_CHUNK(0)  FMA_CHUNK(1)  FMA_CHUNK(2)  FMA_CHUNK(3)
        FMA_CHUNK(4)  FMA_CHUNK(5)  FMA_CHUNK(6)  FMA_CHUNK(7)
        FMA_CHUNK(8)  FMA_CHUNK(9)  FMA_CHUNK(10) FMA_CHUNK(11)
        FMA_CHUNK(12) FMA_CHUNK(13) FMA_CHUNK(14) FMA_CHUNK(15)

        acc0 = group8_sum(acc0);   // valid in sub==7
        acc1 = group8_sum(acc1);

        float h0 = 0.f, h1 = 0.f;
        if (wrt) {
            h0 = fast_tanh(p_cur0 + acc0);
            h1 = fast_tanh(p_cur1 + acc1);
            // publish for peer quads (agent-scope stores; ordered by release flag)
            __hip_atomic_store(&bufbase[par*128 + g],      h0,
                               __ATOMIC_RELAXED, __HIP_MEMORY_SCOPE_AGENT);
            __hip_atomic_store(&bufbase[par*128 + 64 + g], h1,
                               __ATOMIC_RELAXED, __HIP_MEMORY_SCOPE_AGENT);
            if (hs_all) {
                HS[(prow + step) * NH + jg0] = h0;
                HS[(prow + step) * NH + jg1] = h1;
            } else if (step == NT-1) {
                HS[(size_t)b * NH + jg0] = h0;
                HS[(size_t)b * NH + jg1] = h1;
            }
        }
        if (step == NT - 1) break;

        __syncthreads();                       // A: all waves' stores issued+drained
        if (t == 0)
            __hip_atomic_store(myflag, step + 1, __ATOMIC_RELEASE, __HIP_MEMORY_SCOPE_AGENT);
        if (wrt) {                             // own slice straight from registers
            h_sh[par ^ 1][(jg0 >> 6)*68 + (jg0 & 63)] = h0;
            h_sh[par ^ 1][(jg1 >> 6)*68 + (jg1 & 63)] = h1;
        }
        if (t < 384) {                         // distributed peer-wait + gather
            int guard = 0;
            while (__hip_atomic_load(peerflag, __ATOMIC_ACQUIRE, __HIP_MEMORY_SCOPE_AGENT) < step + 1) {
                if (++guard > (1 << 22)) break; // bounded: fail visibly, never hang
            }
            const float v = __hip_atomic_load(&peerbuf[par*128 + e],
                                              __ATOMIC_RELAXED, __HIP_MEMORY_SCOPE_AGENT);
            const int jj  = qp*128 + e;
            h_sh[par ^ 1][(jj >> 6)*68 + (jj & 63)] = v;
        }
        __syncthreads();                       // C: h_sh[par^1] complete = h_t
    }
}

// ---------------------------------------------------------------------------
// Classifier: out[b][c] = h_last[b] . Wc[c] + bc[c]
// ---------------------------------------------------------------------------
__global__ __launch_bounds__(128)
void cls_kernel(const float* __restrict__ h_last, const float* __restrict__ Wc,
                const float* __restrict__ bc, float* __restrict__ out)
{
    const int t = threadIdx.x;
    const int b = t >> 1, c = t & 1;
    const float* hr = &h_last[(size_t)b * NH];
    const float* wr = &Wc[(size_t)c * NH];
    float s = 0.f;
#pragma unroll 8
    for (int i = 0; i < NH; i += 4) {
        const float4 hv = *reinterpret_cast<const float4*>(&hr[i]);
        const float4 wv = *reinterpret_cast<const float4*>(&wr[i]);
        s = fmaf(hv.x, wv.x, s); s = fmaf(hv.y, wv.y, s);
        s = fmaf(hv.z, wv.z, s); s = fmaf(hv.w, wv.w, s);
    }
    out[b*2 + c] = s + bc[c];
}

// ---------------------------------------------------------------------------
extern "C" void kernel_launch(void* const* d_in, const int* in_sizes, int n_in,
                              void* d_out, int out_size, void* d_ws, size_t ws_size,
                              hipStream_t stream)
{
    (void)in_sizes; (void)n_in; (void)out_size; (void)ws_size;

    const float* x    = (const float*)d_in[0];
    const float* Wih0 = (const float*)d_in[1];
    const float* Whh0 = (const float*)d_in[2];
    const float* bih0 = (const float*)d_in[3];
    const float* bhh0 = (const float*)d_in[4];
    const float* Wih1 = (const float*)d_in[5];
    const float* Whh1 = (const float*)d_in[6];
    const float* bih1 = (const float*)d_in[7];
    const float* bhh1 = (const float*)d_in[8];
    const float* Wc   = (const float*)d_in[9];
    const float* bc   = (const float*)d_in[10];
    float* out = (float*)d_out;

    // Workspace (floats): P @0, HS0 @16777216, h_last @33554432,
    // xbuf @33587200 [64][4][2][128], flags @33652736 [2][256] ints.
    float* ws   = (float*)d_ws;
    float* P    = ws;
    float* HS0  = ws + 16777216;
    float* hl   = ws + 33554432;
    float* xbuf = ws + 33587200;
    int*   flg  = (int*)(ws + 33652736);

    // ws is re-poisoned (0xAA) before every timed launch: flags MUST be zeroed.
    hipMemsetAsync(flg, 0, 512 * sizeof(int), stream);

    proj_kernel<256><<<1024, 256, 0, stream>>>(x,   Wih0, bih0, bhh0, P);
    rec_kernel<<<256, 512, 0, stream>>>(P, Whh0, HS0, xbuf, flg,       1);
    proj_kernel<512><<<1024, 256, 0, stream>>>(HS0, Wih1, bih1, bhh1, P);
    rec_kernel<<<256, 512, 0, stream>>>(P, Whh1, hl,  xbuf, flg + 256, 0);
    cls_kernel<<<1, 128, 0, stream>>>(hl, Wc, bc, out);
}

// Round 9
// 18540.791 us; speedup vs baseline: 1.2593x; 1.2593x over previous
//
#include <hip/hip_runtime.h>
#include <cstddef>

#define NBATCH 64
#define NT     512
#define NH     512

// ---------------------------------------------------------------------------
// Projection GEMM: P[m][n] = sum_k A[m][k]*W[n][k] + b1[n] + b2[n]
// (Unchanged — correctness-proven; rec dominates runtime.)
// ---------------------------------------------------------------------------
template<int K>
__global__ __launch_bounds__(256)
void proj_kernel(const float* __restrict__ A, const float* __restrict__ W,
                 const float* __restrict__ b1, const float* __restrict__ b2,
                 float* __restrict__ P)
{
    __shared__ float a_sh[32 * 132];
    __shared__ float b_sh[32 * 132];

    const int t    = threadIdx.x;
    const int bm   = blockIdx.x & 255;
    const int bn   = blockIdx.x >> 8;
    const int row0 = bm * 128;
    const int col0 = bn * 128;

    const int rm = t & 15;
    const int cn = t >> 4;
    const int sr = t >> 3;
    const int kq = t & 7;

    float acc[8][8];
#pragma unroll
    for (int i = 0; i < 8; ++i)
#pragma unroll
        for (int j = 0; j < 8; ++j) acc[i][j] = 0.f;

    for (int k0 = 0; k0 < K; k0 += 32) {
        __syncthreads();
#pragma unroll
        for (int u = 0; u < 4; ++u) {
            const int r = sr + 32 * u;
            const float4 av = *reinterpret_cast<const float4*>(&A[(size_t)(row0 + r) * K + k0 + kq * 4]);
            const float4 wv = *reinterpret_cast<const float4*>(&W[(size_t)(col0 + r) * K + k0 + kq * 4]);
            a_sh[(kq*4+0)*132 + r] = av.x;  a_sh[(kq*4+1)*132 + r] = av.y;
            a_sh[(kq*4+2)*132 + r] = av.z;  a_sh[(kq*4+3)*132 + r] = av.w;
            b_sh[(kq*4+0)*132 + r] = wv.x;  b_sh[(kq*4+1)*132 + r] = wv.y;
            b_sh[(kq*4+2)*132 + r] = wv.z;  b_sh[(kq*4+3)*132 + r] = wv.w;
        }
        __syncthreads();
#pragma unroll 4
        for (int k = 0; k < 32; ++k) {
            const float4 a0 = *reinterpret_cast<const float4*>(&a_sh[k*132 + rm*4]);
            const float4 a1 = *reinterpret_cast<const float4*>(&a_sh[k*132 + 64 + rm*4]);
            const float4 w0 = *reinterpret_cast<const float4*>(&b_sh[k*132 + cn*4]);
            const float4 w1 = *reinterpret_cast<const float4*>(&b_sh[k*132 + 64 + cn*4]);
            const float ar[8] = {a0.x,a0.y,a0.z,a0.w,a1.x,a1.y,a1.z,a1.w};
            const float br[8] = {w0.x,w0.y,w0.z,w0.w,w1.x,w1.y,w1.z,w1.w};
#pragma unroll
            for (int i = 0; i < 8; ++i)
#pragma unroll
                for (int j = 0; j < 8; ++j)
                    acc[i][j] = fmaf(ar[i], br[j], acc[i][j]);
        }
    }

    float bs[8];
#pragma unroll
    for (int j = 0; j < 8; ++j) {
        const int n = col0 + ((j < 4) ? (cn*4 + j) : (64 + cn*4 + j - 4));
        bs[j] = b1[n] + b2[n];
    }
#pragma unroll
    for (int i = 0; i < 8; ++i) {
        const int m = row0 + ((i < 4) ? (rm*4 + i) : (64 + rm*4 + i - 4));
        float4 v0, v1;
        v0.x = acc[i][0]+bs[0]; v0.y = acc[i][1]+bs[1]; v0.z = acc[i][2]+bs[2]; v0.w = acc[i][3]+bs[3];
        v1.x = acc[i][4]+bs[4]; v1.y = acc[i][5]+bs[5]; v1.z = acc[i][6]+bs[6]; v1.w = acc[i][7]+bs[7];
        *reinterpret_cast<float4*>(&P[(size_t)m * NH + col0 + cn*4])      = v0;
        *reinterpret_cast<float4*>(&P[(size_t)m * NH + col0 + 64 + cn*4]) = v1;
    }
}

__device__ __forceinline__ float fast_tanh(float x) {
    x = fminf(15.f, fmaxf(-15.f, x));
    const float e = __expf(2.f * x);
    return (e - 1.f) / (e + 1.f);
}

// ---------------------------------------------------------------------------
// Recurrence: h_t = tanh(P[t] + W_hh @ h_{t-1}) per batch element.
// ROUND-4 STRUCTURE (proven correct, 9.07 ms/layer): one block per batch
// element, 64 blocks x 1024 threads, ZERO cross-block traffic. W_hh streamed
// from the XCD L2 every step. Thread t: row r = t>>1, k-half kh = t&1.
// THIS ROUND'S ONE CHANGE: non-temporal P loads + non-temporal HS stores.
// Round-4 counters showed FETCH=9GB (ideal ~8MB): the P/HS streams were
// evicting W from the XCD L2s ~270x per dispatch. nt keeps the streams out
// of L1/L2 so W stays resident; per-step W then comes from L2 at port rate
// (~3-7us/step) instead of re-fetching from LLC/HBM (~17.7us/step measured).
// Register-resident W is impossible: hipcc sinks invariant loads into the
// loop at VGPR~88 under pressure heuristics (3 structural attempts, r3/7/8).
// ---------------------------------------------------------------------------
__global__ __launch_bounds__(1024, 4)
void rec_kernel(const float* __restrict__ P,
                const float* __restrict__ Whh,
                float* __restrict__ HS,      // hs_all=1: [B*T][H]; else h_last [B][H]
                int hs_all)
{
    const int t  = threadIdx.x;
    const int b  = blockIdx.x;
    const int r  = t >> 1;          // output row 0..511
    const int kh = t & 1;           // k-half: [kh*256, kh*256+256)

    __shared__ float h_sh[2][512];  // double buffer: read [par], write [par^1]
    reinterpret_cast<float*>(h_sh)[t] = 0.f;   // zero both buffers (h0 = 0)

    const float* wrow = Whh + (size_t)r * NH + kh * 256;
    const size_t prow = (size_t)b * NT;
    float p_next = (kh == 0) ? __builtin_nontemporal_load(&P[prow * NH + r]) : 0.f;

    __syncthreads();

    for (int step = 0; step < NT; ++step) {
        const int par = step & 1;
        const float p_cur = p_next;
        if (kh == 0 && step + 1 < NT)          // prefetch next timestep's proj (nt)
            p_next = __builtin_nontemporal_load(&P[(prow + step + 1) * NH + r]);

        // Half-row dot: 64 float4 loads of W (L2-resident) x LDS-broadcast h.
        // Within a wave: even lanes one h address, odd lanes one other ->
        // 2-address broadcast, conflict-free (2-way is free, m136).
        float acc = 0.f;
        const float* hbase = &h_sh[par][kh * 256];
#pragma unroll
        for (int k4 = 0; k4 < 64; ++k4) {
            const float4 w = *reinterpret_cast<const float4*>(&wrow[k4 * 4]);
            const float4 h = *reinterpret_cast<const float4*>(&hbase[k4 * 4]);
            acc = fmaf(w.x, h.x, acc);
            acc = fmaf(w.y, h.y, acc);
            acc = fmaf(w.z, h.z, acc);
            acc = fmaf(w.w, h.w, acc);
        }
        // Pair reduce: DPP quad_perm(1,0,3,2) swaps lane pairs — pure VALU.
        const int sw = __builtin_amdgcn_update_dpp(0, __float_as_int(acc),
                                                   0xB1, 0xF, 0xF, true);
        acc += __int_as_float(sw);

        if (kh == 0) {
            const float hv = fast_tanh(p_cur + acc);
            h_sh[par ^ 1][r] = hv;             // 32 consecutive dwords/wave
            if (hs_all)             __builtin_nontemporal_store(hv, &HS[(prow + step) * NH + r]);
            else if (step == NT-1)  __builtin_nontemporal_store(hv, &HS[(size_t)b * NH + r]);
        }
        __syncthreads();   // writes to [par^1] visible before next step reads them
    }
}

// ---------------------------------------------------------------------------
// Classifier: out[b][c] = h_last[b] . Wc[c] + bc[c]   (64x2, tiny)
// ---------------------------------------------------------------------------
__global__ __launch_bounds__(128)
void cls_kernel(const float* __restrict__ h_last, const float* __restrict__ Wc,
                const float* __restrict__ bc, float* __restrict__ out)
{
    const int t = threadIdx.x;       // 128 threads = 64 batch x 2 classes
    const int b = t >> 1, c = t & 1;
    const float* hr = &h_last[(size_t)b * NH];
    const float* wr = &Wc[(size_t)c * NH];
    float s = 0.f;
#pragma unroll 8
    for (int i = 0; i < NH; i += 4) {
        const float4 hv = *reinterpret_cast<const float4*>(&hr[i]);
        const float4 wv = *reinterpret_cast<const float4*>(&wr[i]);
        s = fmaf(hv.x, wv.x, s); s = fmaf(hv.y, wv.y, s);
        s = fmaf(hv.z, wv.z, s); s = fmaf(hv.w, wv.w, s);
    }
    out[b*2 + c] = s + bc[c];
}

// ---------------------------------------------------------------------------
extern "C" void kernel_launch(void* const* d_in, const int* in_sizes, int n_in,
                              void* d_out, int out_size, void* d_ws, size_t ws_size,
                              hipStream_t stream)
{
    (void)in_sizes; (void)n_in; (void)out_size; (void)ws_size;

    const float* x    = (const float*)d_in[0];
    const float* Wih0 = (const float*)d_in[1];
    const float* Whh0 = (const float*)d_in[2];
    const float* bih0 = (const float*)d_in[3];
    const float* bhh0 = (const float*)d_in[4];
    const float* Wih1 = (const float*)d_in[5];
    const float* Whh1 = (const float*)d_in[6];
    const float* bih1 = (const float*)d_in[7];
    const float* bhh1 = (const float*)d_in[8];
    const float* Wc   = (const float*)d_in[9];
    const float* bc   = (const float*)d_in[10];
    float* out = (float*)d_out;

    // Workspace layout (floats):
    //   P     [32768*512] @ 0         (reused for proj0 then proj1)
    //   HS0   [32768*512] @ 16777216
    //   h_last[64*512]    @ 33554432
    float* ws  = (float*)d_ws;
    float* P   = ws;
    float* HS0 = ws + 16777216;
    float* hl  = ws + 33554432;

    proj_kernel<256><<<1024, 256, 0, stream>>>(x,   Wih0, bih0, bhh0, P);
    rec_kernel<<<NBATCH, 1024, 0, stream>>>(P, Whh0, HS0, 1);
    proj_kernel<512><<<1024, 256, 0, stream>>>(HS0, Wih1, bih1, bhh1, P);
    rec_kernel<<<NBATCH, 1024, 0, stream>>>(P, Whh1, hl,  0);
    cls_kernel<<<1, 128, 0, stream>>>(hl, Wc, bc, out);
}